// Round 5
// baseline (25.326 us; speedup 1.0000x reference)
//
#include <hip/hip_runtime.h>

// 4-qubit circuit, B=2^20, two kernels.
// out_w(x) = sum_{a,b in 9x9} K_w[b][a] * F01[a](x0,x1) * F23[b](x2,x3)
// F01/F23: outer products of per-qubit basis {1, cos(pi*x_q), sin(pi*x_q)}.
// K (4x81, rows padded to 12) depends only on weights:
//   U (shuffle-parallel) -> A_w = Re(U^dag Z_w U) -> K (validated R1-R3).
// Wire w <-> bit (3-w) of flat state index j (wire 0 = MSB).

__device__ __align__(16) float g_K[4 * 9 * 12];  // [w][b][a]

// ---------------- prep: weights -> g_K (one block; identical to R3) -----------
__global__ __launch_bounds__(384) void qc_prep(const float* __restrict__ w) {
    __shared__ float sUr[16][16], sUi[16][16];   // [j][k]
    __shared__ float sA[4][16][16];              // [w][k][l]
    const int tid = threadIdx.x;

    if (tid < 256) {
        const int k = tid >> 4;
        const int j = tid & 15;
        float vr = (j == k) ? 1.f : 0.f;
        float vi = 0.f;
#pragma unroll
        for (int d = 0; d < 2; ++d) {
#pragma unroll
            for (int p = 0; p < 4; ++p) {           // CNOT ring
                const int mc = 8 >> p;
                const int mt = 8 >> ((p + 1) & 3);
                const float ur = __shfl_xor(vr, mt);
                const float ui = __shfl_xor(vi, mt);
                if (j & mc) { vr = ur; vi = ui; }
            }
#pragma unroll
            for (int i = 0; i < 4; ++i) {
                const int mw = 8 >> i;
                const float th = 0.5f * w[(d * 4 + i) * 2 + 0];
                const float c = __cosf(th), s = __sinf(th);
                const float uyr = __shfl_xor(vr, mw);
                const float uyi = __shfl_xor(vi, mw);
                const float sgn = (j & mw) ? s : -s;
                vr = fmaf(sgn, uyr, c * vr);
                vi = fmaf(sgn, uyi, c * vi);
                const float ph = 0.5f * w[(d * 4 + i) * 2 + 1];
                const float cp = __cosf(ph), sp = __sinf(ph);
                const float pim = (j & mw) ? sp : -sp;
                const float t = cp * vr - pim * vi;
                vi = fmaf(cp, vi, pim * vr);
                vr = t;
            }
        }
        sUr[j][k] = vr;
        sUi[j][k] = vi;
    }
    __syncthreads();

    if (tid < 256) {
        const int k = tid >> 4, l = tid & 15;
        float g[16];
#pragma unroll
        for (int j = 0; j < 16; ++j)
            g[j] = sUr[j][k] * sUr[j][l] + sUi[j][k] * sUi[j][l];
#pragma unroll
        for (int w4 = 0; w4 < 4; ++w4) {
            float a = 0.f;
#pragma unroll
            for (int j = 0; j < 16; ++j)
                a += ((j >> (3 - w4)) & 1) ? -g[j] : g[j];
            sA[w4][k][l] = a;
        }
    }
    __syncthreads();

    if (tid < 324) {
        const int w4 = tid / 81, r = tid % 81;
        const int bb = r / 9, aa = r % 9;
        const int al[4] = { aa / 3, aa % 3, bb / 3, bb % 3 };
        float acc = 0.f;
#pragma unroll
        for (int t = 0; t < 16; ++t) {
            int k = 0, l = 0;
            float sgn = 1.f;
#pragma unroll
            for (int q = 0; q < 4; ++q) {
                const int alpha = al[q];
                const int c = (t >> q) & 1;
                int bk, bl;
                if (alpha == 2) { bk = c; bl = c ^ 1; }
                else           { bk = c; bl = c; if (alpha == 1 && c) sgn = -sgn; }
                k |= bk << (3 - q);
                l |= bl << (3 - q);
            }
            acc += sgn * sA[w4][k][l];
        }
        g_K[(w4 * 9 + bb) * 12 + aa] = acc * 0.0625f;
    }
}

// ---------------- main: 1 sample/thread, max occupancy ------------------------
__global__ __launch_bounds__(256, 8) void qc_main(const float4* __restrict__ x4,
                                                  float4* __restrict__ out4) {
    const int i = blockIdx.x * 256 + threadIdx.x;
    const float4 xv = x4[i];

    // sin(pi*x) = v_sin(x/2 revolutions); |x/2| < ~3 rev, inside HW range.
    float S0, C0, S1, C1, S2, C2, S3, C3;
    {
        const float h0 = 0.5f * xv.x, h1 = 0.5f * xv.y;
        const float h2 = 0.5f * xv.z, h3 = 0.5f * xv.w;
        asm("v_sin_f32 %0, %1" : "=v"(S0) : "v"(h0));
        asm("v_cos_f32 %0, %1" : "=v"(C0) : "v"(h0));
        asm("v_sin_f32 %0, %1" : "=v"(S1) : "v"(h1));
        asm("v_cos_f32 %0, %1" : "=v"(C1) : "v"(h1));
        asm("v_sin_f32 %0, %1" : "=v"(S2) : "v"(h2));
        asm("v_cos_f32 %0, %1" : "=v"(C2) : "v"(h2));
        asm("v_sin_f32 %0, %1" : "=v"(S3) : "v"(h3));
        asm("v_cos_f32 %0, %1" : "=v"(C3) : "v"(h3));
    }

    const float f01_0 = C1,      f01_1 = S1,      f01_2 = C0;
    const float f01_3 = C0 * C1, f01_4 = C0 * S1, f01_5 = S0;
    const float f01_6 = S0 * C1, f01_7 = S0 * S1;
    const float f23_0 = C3,      f23_1 = S3,      f23_2 = C2;
    const float f23_3 = C2 * C3, f23_4 = C2 * S3, f23_5 = S2;
    const float f23_6 = S2 * C3, f23_7 = S2 * S3;
    const float f23a[8] = { f23_0, f23_1, f23_2, f23_3, f23_4, f23_5, f23_6, f23_7 };

    float o[4];
#pragma unroll
    for (int W = 0; W < 4; ++W) {
        float acc = 0.f;
#pragma unroll
        for (int b = 0; b < 9; ++b) {
            const float* Kr = g_K + (W * 9 + b) * 12;
            const float4 k0 = *reinterpret_cast<const float4*>(Kr);
            const float4 k1 = *reinterpret_cast<const float4*>(Kr + 4);
            const float  k8 = Kr[8];
            float tt = k0.x;
            tt = fmaf(k0.y, f01_0, tt);
            tt = fmaf(k0.z, f01_1, tt);
            tt = fmaf(k0.w, f01_2, tt);
            tt = fmaf(k1.x, f01_3, tt);
            tt = fmaf(k1.y, f01_4, tt);
            tt = fmaf(k1.z, f01_5, tt);
            tt = fmaf(k1.w, f01_6, tt);
            tt = fmaf(k8,   f01_7, tt);
            acc = (b == 0) ? tt : fmaf(tt, f23a[b - 1], acc);
        }
        o[W] = acc;
    }

    out4[i] = make_float4(o[0], o[1], o[2], o[3]);
}

extern "C" void kernel_launch(void* const* d_in, const int* in_sizes, int n_in,
                              void* d_out, int out_size, void* d_ws, size_t ws_size,
                              hipStream_t stream) {
    const float* x = (const float*)d_in[0];
    const float* w = (const float*)d_in[1];
    const int B = in_sizes[0] / 4;  // 1,048,576

    hipLaunchKernelGGL(qc_prep, dim3(1), dim3(384), 0, stream, w);
    hipLaunchKernelGGL(qc_main, dim3(B / 256), dim3(256), 0, stream,
                       (const float4*)x, (float4*)d_out);
}